// Round 6
// baseline (5367.434 us; speedup 1.0000x reference)
//
#include <hip/hip_runtime.h>
#include <math.h>

// ============================================================================
// RSSM forward on MI355X.
// Round 9: ONE barrier per step. R8 post-mortem: distributed-flag barrier +
// hoisted loads added stall (busy% fell while time doubled) -> reverted to the
// R7 central-counter gsync (proven 2.26us/segment). The real lever is fewer
// segments: only the GRU's weights (768KB) are too big to re-read per step --
// keep them column-split in LDS. Every other stage (gin 64KB, po1h 128KB,
// po2 128KB, pom/pov 128KB) is REPLICATED per member, weights streamed from
// the (shared, hot) L2 at ~448KB/CU/step, pipelined behind 272 MFMAs/wave.
// Chain per step: gin(local) -> GRU(slice) -> [H barrier] -> read full h ->
// po1h/po2/heads/sample all local. XG/XM1/XM2/XS exchanges gone; prologue
// barrier-free. Same per-element FP op order as R7 -> bit-identical output.
// post_pass reverted to the R7 16-row/4064-block version (64-row was -330us).
// ============================================================================

using v8s   = __attribute__((ext_vector_type(8))) short;
using f32x4 = __attribute__((ext_vector_type(4))) float;
typedef unsigned long long u64;

#define BN   512
#define TN   128
#define LATN 128

#define AB_S 264   // 256-col LDS activation stride (shorts)

// pre-shuffled weight tile bases (1 tile = 16n x 32k bf16 = 1KB = 512 shorts)
#define OBS1_T 0
#define OBS2_T 256
#define PO1O_T 384
#define PO1H_T 512
#define GINS_T 640
#define IH_T   704
#define HH_T   1088
#define PR1_T  1472
#define PR2_T  1600
#define PRM_T  1728
#define PRV_T  1792
#define PO2_T  1856
#define POM_T  1984
#define POV_T  2048
#define TOT_TILES 2112

#define B1_BYTES 33554432UL          // 65536 x 256 bf16
#define KL_OFF   8388608UL           // states elements (512*128*128)

__device__ __forceinline__ unsigned short f2bf(float f){
  union { float f; unsigned u; } v; v.f = f;
  unsigned u = v.u + 0x7fffu + ((v.u >> 16) & 1u);   // RNE
  return (unsigned short)(u >> 16);
}
__device__ __forceinline__ float bf2f(unsigned short s){
  union { unsigned u; float f; } v; v.u = ((unsigned)s) << 16; return v.f;
}
__device__ __forceinline__ float sigm(float x){ return 1.f / (1.f + __expf(-x)); }
__device__ __forceinline__ float tanhx(float x){ return 1.f - 2.f/(__expf(2.f*x) + 1.f); }

#define MFMA16(a,b,c) __builtin_amdgcn_mfma_f32_16x16x32_bf16((a),(b),(c),0,0,0)
#define LDB(tIdx) (*(const v8s*)(wt + ((size_t)(tIdx))*512 + lane*8))

// device-coherent exchange primitives
__device__ __forceinline__ v8s ldx16(const unsigned short* p){
  union { u64 u[2]; v8s v; } x;
  x.u[0] = __hip_atomic_load((u64*)p,     __ATOMIC_RELAXED, __HIP_MEMORY_SCOPE_AGENT);
  x.u[1] = __hip_atomic_load((u64*)p + 1, __ATOMIC_RELAXED, __HIP_MEMORY_SCOPE_AGENT);
  return x.v;
}
__device__ __forceinline__ void stxs(unsigned short* p, unsigned short v){
  __hip_atomic_store(p, v, __ATOMIC_RELAXED, __HIP_MEMORY_SCOPE_AGENT);
}

// ---------------------------------------------------------------------------
// Weight shuffle: f32 (N,K) row-major -> bf16 fragment-linear tiles.
// ---------------------------------------------------------------------------
struct ShufArgs {
  const float* src[14];
  int stride[14], coloff[14], ktiles[14], tbase[14], tcnt[14];
};

__global__ __launch_bounds__(64) void shuffle_w(ShufArgs sa, unsigned short* __restrict__ wt)
{
  int tile = blockIdx.x;
  int s = 0;
  while (tile >= sa.tbase[s] + sa.tcnt[s]) s++;
  int lt = tile - sa.tbase[s];
  int kt = lt % sa.ktiles[s];
  int nt = lt / sa.ktiles[s];
  int l  = threadIdx.x;
  int n  = nt*16 + (l & 15);
  int k  = sa.coloff[s] + kt*32 + (l >> 4)*8;
  const float* sp = sa.src[s] + (size_t)n * sa.stride[s] + k;
  unsigned short* dp = wt + (size_t)tile*512 + (size_t)l*8;
  #pragma unroll
  for (int j = 0; j < 8; j++) dp[j] = f2bf(sp[j]);
}

// ---------------------------------------------------------------------------
// Parallel GEMM for obs MLP / po1_o precompute.
// ---------------------------------------------------------------------------
__global__ __launch_bounds__(256) void big_gemm(
    const void* __restrict__ Ain, int aIsF32, int K,
    const unsigned short* __restrict__ wt, int tbase,
    const float* __restrict__ bias, int doRelu,
    unsigned short* __restrict__ outB)
{
  __shared__ unsigned short AL[64*AB_S];
  int tid = threadIdx.x, lane = tid & 63, wv = tid >> 6;
  int q = lane >> 4, c16 = lane & 15;
  size_t row0 = (size_t)blockIdx.x * 64;

  f32x4 acc[16];
  #pragma unroll
  for (int nt = 0; nt < 16; nt++) acc[nt] = (f32x4){0.f,0.f,0.f,0.f};

  int nchunk = K >> 8;
  int ktT    = K >> 5;
  for (int cc = 0; cc < nchunk; cc++){
    int r = tid >> 2, c0 = (tid & 3) * 64;
    if (aIsF32){
      const float* A = (const float*)Ain + (row0 + r) * (size_t)K + (size_t)cc*256 + c0;
      #pragma unroll
      for (int ii = 0; ii < 16; ii++){
        float4 x = ((const float4*)A)[ii];
        ushort4 o;
        o.x = f2bf(x.x); o.y = f2bf(x.y); o.z = f2bf(x.z); o.w = f2bf(x.w);
        *(ushort4*)&AL[r*AB_S + c0 + ii*4] = o;
      }
    } else {
      const unsigned short* A = (const unsigned short*)Ain + (row0 + r)*256 + c0;
      #pragma unroll
      for (int ii = 0; ii < 8; ii++)
        *(v8s*)&AL[r*AB_S + c0 + ii*8] = *(const v8s*)(A + ii*8);
    }
    __syncthreads();
    const unsigned short* myA = &AL[wv*16*AB_S];
    #pragma unroll
    for (int kt = 0; kt < 8; kt++){
      v8s af = *(const v8s*)&myA[c16*AB_S + kt*32 + q*8];
      #pragma unroll
      for (int nt = 0; nt < 16; nt++){
        v8s bf = *(const v8s*)(wt + ((size_t)(tbase + nt*ktT + cc*8 + kt))*512 + lane*8);
        acc[nt] = MFMA16(af, bf, acc[nt]);
      }
    }
    __syncthreads();
  }
  #pragma unroll
  for (int nt = 0; nt < 16; nt++){
    int col = nt*16 + c16;
    float b = bias[col];
    #pragma unroll
    for (int i = 0; i < 4; i++){
      float v = acc[nt][i] + b;
      if (doRelu) v = fmaxf(v, 0.f);
      outB[(row0 + wv*16 + q*4 + i)*256 + col] = f2bf(v);
    }
  }
}

// ---------------------------------------------------------------------------
// post_pass helpers (16 rows x 256 cols, 16 waves; wave wv owns nt = wv).
// ---------------------------------------------------------------------------
__device__ __forceinline__ void stage256(
    const unsigned short* __restrict__ inA,
    const unsigned short* __restrict__ wt, int tbase,
    const float* __restrict__ bias,
    unsigned short* __restrict__ outA, int lane, int wv)
{
  int q = lane >> 4, c16 = lane & 15;
  v8s wf[8];
  #pragma unroll
  for (int kt = 0; kt < 8; kt++) wf[kt] = LDB(tbase + wv*8 + kt);
  v8s af[8];
  #pragma unroll
  for (int kt = 0; kt < 8; kt++) af[kt] = *(const v8s*)&inA[c16*AB_S + kt*32 + q*8];
  f32x4 acc = (f32x4){0.f,0.f,0.f,0.f};
  #pragma unroll
  for (int kt = 0; kt < 8; kt++) acc = MFMA16(af[kt], wf[kt], acc);
  int col = wv*16 + c16;
  float b = bias[col];
  #pragma unroll
  for (int i = 0; i < 4; i++)
    outA[(q*4 + i)*AB_S + col] = f2bf(fmaxf(acc[i] + b, 0.f));
}

__device__ __forceinline__ void pheads(
    const unsigned short* __restrict__ X2,
    const unsigned short* __restrict__ wt, int tM, int tV,
    const float* __restrict__ bM, const float* __restrict__ bV,
    float* __restrict__ muF, float* __restrict__ varF, int lane, int wv)
{
  int q = lane >> 4, c16 = lane & 15;
  int mtx = wv >> 3, nt = wv & 7;
  int tb  = mtx ? tV : tM;
  v8s wf[8];
  #pragma unroll
  for (int kt = 0; kt < 8; kt++) wf[kt] = LDB(tb + nt*8 + kt);
  v8s af[8];
  #pragma unroll
  for (int kt = 0; kt < 8; kt++) af[kt] = *(const v8s*)&X2[c16*AB_S + kt*32 + q*8];
  f32x4 acc = (f32x4){0.f,0.f,0.f,0.f};
  #pragma unroll
  for (int kt = 0; kt < 8; kt++) acc = MFMA16(af[kt], wf[kt], acc);
  int col = nt*16 + c16;
  float b = mtx ? bV[col] : bM[col];
  float* dst = mtx ? varF : muF;
  #pragma unroll
  for (int i = 0; i < 4; i++){
    float v = acc[i] + b;
    if (mtx) v = __expf(v) + 0.01f;
    dst[(q*4 + i)*LATN + col] = v;
  }
}

__device__ __forceinline__ void pstage_add(
    const unsigned short* __restrict__ inA,
    const unsigned short* __restrict__ wt, int tbase,
    const unsigned short* __restrict__ Pbuf, int row0,
    unsigned short* __restrict__ outA, int lane, int wv)
{
  int q = lane >> 4, c16 = lane & 15;
  v8s wf[8];
  #pragma unroll
  for (int kt = 0; kt < 8; kt++) wf[kt] = LDB(tbase + wv*8 + kt);
  v8s af[8];
  #pragma unroll
  for (int kt = 0; kt < 8; kt++) af[kt] = *(const v8s*)&inA[c16*AB_S + kt*32 + q*8];
  int col = wv*16 + c16;
  unsigned short pv[4];
  #pragma unroll
  for (int i = 0; i < 4; i++){
    int grow = row0 + q*4 + i;          // = b*127 + t
    int prow = grow + grow/127 + 1;     // = b*128 + (t+1)
    pv[i] = __builtin_nontemporal_load(&Pbuf[(size_t)prow*256 + col]);
  }
  f32x4 acc = (f32x4){0.f,0.f,0.f,0.f};
  #pragma unroll
  for (int kt = 0; kt < 8; kt++) acc = MFMA16(af[kt], wf[kt], acc);
  #pragma unroll
  for (int i = 0; i < 4; i++){
    float v = acc[i] + bf2f(pv[i]);
    outA[(q*4 + i)*AB_S + col] = f2bf(fmaxf(v, 0.f));
  }
}

// ---------------------------------------------------------------------------
// Group barrier (R7-proven): central monotonic epoch counter, relaxed agent
// atomics. __syncthreads' vmcnt(0) drain puts the write-through exchange
// stores at the coherence point before tid0 increments.
// ---------------------------------------------------------------------------
__device__ __forceinline__ void gsync(unsigned* c, unsigned tgt, int tid)
{
  __syncthreads();
  asm volatile("" ::: "memory");
  if (tid == 0){
    __hip_atomic_fetch_add(c, 1u, __ATOMIC_RELAXED, __HIP_MEMORY_SCOPE_AGENT);
    while (__hip_atomic_load(c, __ATOMIC_RELAXED, __HIP_MEMORY_SCOPE_AGENT) < tgt)
      __builtin_amdgcn_s_sleep(1);
  }
  asm volatile("" ::: "memory");
  __syncthreads();
}

// ---------------------------------------------------------------------------
// Distributed recurrence, 1 barrier/step. Grid 256 = 32 groups x 8 members;
// group g owns batch rows g*16..g*16+15. Member j computes the GRU for cols
// [32j,32j+32) (weights LDS-pinned); everything else (gin, po1h, po2, heads,
// sample) is computed in FULL by every member with weights streamed from L2.
// Only h is exchanged (XH, parity double-buffered). 128 threads = 2 waves.
// ---------------------------------------------------------------------------
struct RnnArgs {
  const unsigned short *wt, *Pbuf;
  const float *actions, *noise, *w_gin, *b_gin, *b_ih, *b_hh, *b_po2, *b_pom, *b_pov;
  unsigned short *Hb, *XH;
  unsigned *cnt;
  float *out;
};

__global__ __launch_bounds__(128, 1) void rssm_rnn(RnnArgs A)
{
  __shared__ unsigned short Lw[96*512];      // ih(48)+hh(48) slices: 96 KiB
  __shared__ float LwaA[2048];               // full w_gin action part [256][8]
  __shared__ float Lbg[256], Lbp2[256];
  __shared__ float Lbih[96], Lbhh[96];
  __shared__ float Lbm[128], Lbv[128];
  __shared__ unsigned short gF [16*264];     // g (full) ; overlaid as muF
  __shared__ unsigned short m1F[16*264];     // m1 (full); overlaid as varF
  __shared__ unsigned short m2F[16*264];     // m2 (full)
  __shared__ unsigned short hA [16*264];     // h_{t-1} then h_t (full)
  __shared__ unsigned short sF [16*136];     // s (full)
  __shared__ float aF[128];

  float* muF  = (float*)gF;                  // 16x128 f32 (8 KiB <= gF)
  float* varF = (float*)m1F;

  const unsigned short* wt = A.wt;
  int tid = threadIdx.x, lane = tid & 63, wv = tid >> 6;
  int q = lane >> 4, c16 = lane & 15;
  int g = blockIdx.x & 31, j = blockIdx.x >> 5;
  int b0 = g * 16;
  int lc = wv*16 + c16;          // local col in the member's 32-wide GRU slice
  int gc = 32*j + lc;            // global col

  // ---- pin GRU weight slices in LDS ----
  for (int u = tid; u < 96*64; u += 128){
    int lt = u >> 6, ch = u & 63;
    int gt;
    if (lt < 48)
      gt = IH_T + ((lt >> 4)*16 + 2*j + ((lt >> 3) & 1))*8 + (lt & 7);
    else {
      int u2 = lt - 48;
      gt = HH_T + ((u2 >> 4)*16 + 2*j + ((u2 >> 3) & 1))*8 + (u2 & 7);
    }
    *(v8s*)&Lw[lt*512 + ch*8] = *(const v8s*)(A.wt + (size_t)gt*512 + ch*8);
  }
  for (int u = tid; u < 2048; u += 128)
    LwaA[u] = A.w_gin[(size_t)(u >> 3)*136 + 128 + (u & 7)];
  for (int u = tid; u < 256; u += 128){ Lbg[u] = A.b_gin[u]; Lbp2[u] = A.b_po2[u]; }
  if (tid < 96){
    Lbih[tid] = A.b_ih[(tid >> 5)*256 + 32*j + (tid & 31)];
    Lbhh[tid] = A.b_hh[(tid >> 5)*256 + 32*j + (tid & 31)];
  }
  Lbm[tid] = A.b_pom[tid];
  Lbv[tid] = A.b_pov[tid];
  for (int u = tid; u < 16*264; u += 128) hA[u] = 0;

  float hFr[4] = {0.f, 0.f, 0.f, 0.f};   // f32 h carry, rows q*4+i, col gc
  __syncthreads();

  unsigned* cH = A.cnt + g;
  const size_t sl = (size_t)(g*8);

  for (int t = -1; t < TN-1; t++){
    if (t >= 0){
      int p = t & 1;
      // ---- gin FULL: g = relu(s @ WginS^T + a @ WginA^T + b_gin) -> gF ----
      {
        v8s af4[4];
        #pragma unroll
        for (int kt = 0; kt < 4; kt++)
          af4[kt] = *(const v8s*)&sF[c16*136 + kt*32 + q*8];
        #pragma unroll
        for (int u = 0; u < 8; u++){
          int nt = u*2 + wv;
          v8s wf[4];
          #pragma unroll
          for (int kt = 0; kt < 4; kt++) wf[kt] = LDB(GINS_T + nt*4 + kt);
          f32x4 acc = (f32x4){0.f,0.f,0.f,0.f};
          #pragma unroll
          for (int kt = 0; kt < 4; kt++) acc = MFMA16(af4[kt], wf[kt], acc);
          int col = nt*16 + c16;
          float bg = Lbg[col];
          #pragma unroll
          for (int i = 0; i < 4; i++){
            int r = q*4 + i;
            float v = acc[i] + bg;
            #pragma unroll
            for (int m = 0; m < 8; m++) v += aF[r*8 + m]*LwaA[col*8 + m];
            gF[r*264 + col] = f2bf(fmaxf(v, 0.f));
          }
        }
      }
      __syncthreads();
      // ---- GRU (member slice; ag/ah from LDS) ----
      {
        v8s ag[8], ah[8];
        #pragma unroll
        for (int kt = 0; kt < 8; kt++){
          ag[kt] = *(const v8s*)&gF[c16*264 + kt*32 + q*8];
          ah[kt] = *(const v8s*)&hA[c16*264 + kt*32 + q*8];
        }
        f32x4 accI[3];
        #pragma unroll
        for (int x = 0; x < 3; x++){
          v8s wf[8];
          #pragma unroll
          for (int kt = 0; kt < 8; kt++)
            wf[kt] = *(const v8s*)&Lw[((x*2 + wv)*8 + kt)*512 + lane*8];
          accI[x] = (f32x4){0.f,0.f,0.f,0.f};
          #pragma unroll
          for (int kt = 0; kt < 8; kt++) accI[x] = MFMA16(ag[kt], wf[kt], accI[x]);
        }
        float rg[4], zg[4];
        {
          v8s wf[8];
          #pragma unroll
          for (int kt = 0; kt < 8; kt++)
            wf[kt] = *(const v8s*)&Lw[(48 + (0*2 + wv)*8 + kt)*512 + lane*8];
          f32x4 a = (f32x4){0.f,0.f,0.f,0.f};
          #pragma unroll
          for (int kt = 0; kt < 8; kt++) a = MFMA16(ah[kt], wf[kt], a);
          float bir = Lbih[lc], bhr = Lbhh[lc];
          #pragma unroll
          for (int i = 0; i < 4; i++) rg[i] = sigm(accI[0][i] + bir + a[i] + bhr);
        }
        {
          v8s wf[8];
          #pragma unroll
          for (int kt = 0; kt < 8; kt++)
            wf[kt] = *(const v8s*)&Lw[(48 + (1*2 + wv)*8 + kt)*512 + lane*8];
          f32x4 a = (f32x4){0.f,0.f,0.f,0.f};
          #pragma unroll
          for (int kt = 0; kt < 8; kt++) a = MFMA16(ah[kt], wf[kt], a);
          float biz = Lbih[32 + lc], bhz = Lbhh[32 + lc];
          #pragma unroll
          for (int i = 0; i < 4; i++) zg[i] = sigm(accI[1][i] + biz + a[i] + bhz);
        }
        {
          v8s wf[8];
          #pragma unroll
          for (int kt = 0; kt < 8; kt++)
            wf[kt] = *(const v8s*)&Lw[(48 + (2*2 + wv)*8 + kt)*512 + lane*8];
          f32x4 a = (f32x4){0.f,0.f,0.f,0.f};
          #pragma unroll
          for (int kt = 0; kt < 8; kt++) a = MFMA16(ah[kt], wf[kt], a);
          float bin = Lbih[64 + lc], bhn = Lbhh[64 + lc];
          #pragma unroll
          for (int i = 0; i < 4; i++){
            int r = q*4 + i;
            float ng = tanhx(accI[2][i] + bin + rg[i]*(a[i] + bhn));
            float hv = (1.f - zg[i])*ng + zg[i]*hFr[i];
            hFr[i] = hv;
            unsigned short hb = f2bf(hv);
            stxs(&A.XH[(((size_t)(1 - p)*256 + sl + j)*16 + r)*32 + lc], hb);
            __builtin_nontemporal_store(hb, &A.Hb[((size_t)(b0 + r)*127 + t)*256 + gc]);
          }
        }
      }
      // ---- the ONE barrier per step ----
      gsync(cH, (unsigned)(8*(t+1)), tid);
      // ---- pull full h_t into hA ----
      for (int u = tid; u < 512; u += 128){
        int k = u >> 6, r = (u >> 2) & 15, c8 = (u & 3)*8;
        *(v8s*)&hA[r*264 + k*32 + c8] =
            ldx16(A.XH + (((size_t)(1 - p)*256 + sl + k)*16 + r)*32 + c8);
      }
      __syncthreads();
      // ---- po1h FULL -> m1F ----
      {
        v8s ah2[8];
        #pragma unroll
        for (int kt = 0; kt < 8; kt++)
          ah2[kt] = *(const v8s*)&hA[c16*264 + kt*32 + q*8];
        #pragma unroll
        for (int u = 0; u < 8; u++){
          int nt = u*2 + wv;
          v8s wf[8];
          #pragma unroll
          for (int kt = 0; kt < 8; kt++) wf[kt] = LDB(PO1H_T + nt*8 + kt);
          int col = nt*16 + c16;
          unsigned short pv[4];
          #pragma unroll
          for (int i = 0; i < 4; i++)
            pv[i] = __builtin_nontemporal_load(
                &A.Pbuf[((size_t)(b0 + q*4 + i)*TN + (t+1))*256 + col]);
          f32x4 acc = (f32x4){0.f,0.f,0.f,0.f};
          #pragma unroll
          for (int kt = 0; kt < 8; kt++) acc = MFMA16(ah2[kt], wf[kt], acc);
          #pragma unroll
          for (int i = 0; i < 4; i++)
            m1F[(q*4 + i)*264 + col] = f2bf(fmaxf(acc[i] + bf2f(pv[i]), 0.f));
        }
      }
    } else {
      // ---- prologue: m1 = relu(po1_o[:, t=0]) (belief = 0), barrier-free ----
      for (int u = tid; u < 4096; u += 128){
        int r = u >> 8, c = u & 255;
        unsigned short pv0 = __builtin_nontemporal_load(
            &A.Pbuf[((size_t)(b0 + r)*TN + 0)*256 + c]);
        m1F[r*264 + c] = f2bf(fmaxf(bf2f(pv0), 0.f));
      }
    }
    __syncthreads();
    // ---- po2 FULL -> m2F ----
    {
      v8s am[8];
      #pragma unroll
      for (int kt = 0; kt < 8; kt++)
        am[kt] = *(const v8s*)&m1F[c16*264 + kt*32 + q*8];
      #pragma unroll
      for (int u = 0; u < 8; u++){
        int nt = u*2 + wv;
        v8s wf[8];
        #pragma unroll
        for (int kt = 0; kt < 8; kt++) wf[kt] = LDB(PO2_T + nt*8 + kt);
        f32x4 acc = (f32x4){0.f,0.f,0.f,0.f};
        #pragma unroll
        for (int kt = 0; kt < 8; kt++) acc = MFMA16(am[kt], wf[kt], acc);
        int col = nt*16 + c16;
        #pragma unroll
        for (int i = 0; i < 4; i++)
          m2F[(q*4 + i)*264 + col] = f2bf(fmaxf(acc[i] + Lbp2[col], 0.f));
      }
    }
    __syncthreads();
    // ---- heads FULL: wave0 = mu (128 cols), wave1 = var ----
    {
      v8s am2[8];
      #pragma unroll
      for (int kt = 0; kt < 8; kt++)
        am2[kt] = *(const v8s*)&m2F[c16*264 + kt*32 + q*8];
      int tb = wv ? POV_T : POM_T;
      #pragma unroll
      for (int nt = 0; nt < 8; nt++){
        v8s wf[8];
        #pragma unroll
        for (int kt = 0; kt < 8; kt++) wf[kt] = LDB(tb + nt*8 + kt);
        f32x4 acc = (f32x4){0.f,0.f,0.f,0.f};
        #pragma unroll
        for (int kt = 0; kt < 8; kt++) acc = MFMA16(am2[kt], wf[kt], acc);
        int col = nt*16 + c16;
        #pragma unroll
        for (int i = 0; i < 4; i++){
          float v = acc[i] + (wv ? Lbv[col] : Lbm[col]);
          if (wv) varF[(q*4 + i)*128 + col] = __expf(v) + 0.01f;
          else    muF [(q*4 + i)*128 + col] = v;
        }
      }
    }
    if (t + 1 < TN - 1)
      aF[tid] = __builtin_nontemporal_load(
          &A.actions[((size_t)(b0 + (tid >> 3))*127 + (t+1))*8 + (tid & 7)]);
    __syncthreads();
    // ---- sample FULL: thread owns row tid>>3, cols [(tid&7)*16, +16) ----
    {
      int r = tid >> 3, c0 = (tid & 7)*16;
      float4 ep4[4];
      #pragma unroll
      for (int w = 0; w < 4; w++)
        ep4[w] = *(const float4*)&A.noise[((size_t)(t+1)*BN + b0 + r)*LATN + c0 + w*4];
      #pragma unroll
      for (int ii = 0; ii < 16; ii++){
        int c = c0 + ii;
        float ep = ((const float*)ep4)[ii];
        float sv = muF[r*128 + c] + sqrtf(varF[r*128 + c])*ep;
        sF[r*136 + c] = f2bf(sv);
        if ((tid & 7) == j)
          __builtin_nontemporal_store(sv,
              &A.out[((size_t)(b0 + r)*TN + (t+1))*LATN + c]);
      }
    }
    __syncthreads();
  }
}

// ---------------------------------------------------------------------------
// Parallel post-pass over all (b,t) rows (R7 version: 16 rows, 4064 blocks).
// ---------------------------------------------------------------------------
__global__ __launch_bounds__(1024, 4) void post_pass(
    const unsigned short* __restrict__ wt,
    const unsigned short* __restrict__ Pbuf,
    const unsigned short* __restrict__ Hb,
    const float* __restrict__ b_pr1, const float* __restrict__ b_pr2,
    const float* __restrict__ b_prm, const float* __restrict__ b_prv,
    const float* __restrict__ b_po2, const float* __restrict__ b_pom,
    const float* __restrict__ b_pov,
    float* __restrict__ out)
{
  __shared__ unsigned short hC[16*AB_S];
  __shared__ unsigned short X1[16*AB_S];
  __shared__ unsigned short X2[16*AB_S];
  __shared__ float mupF[16*LATN], varpF[16*LATN];
  __shared__ float muqF[16*LATN], varqF[16*LATN];

  int tid = threadIdx.x, lane = tid & 63, wv = tid >> 6;
  int row0 = blockIdx.x * 16;

  if (tid < 512){
    int r = tid >> 5, c8 = (tid & 31)*8;
    *(v8s*)&hC[r*AB_S + c8] = *(const v8s*)&Hb[(size_t)(row0 + r)*256 + c8];
  }
  __syncthreads();

  stage256(hC, wt, PR1_T, b_pr1, X1, lane, wv);
  __syncthreads();
  stage256(X1, wt, PR2_T, b_pr2, X2, lane, wv);
  __syncthreads();
  pheads(X2, wt, PRM_T, PRV_T, b_prm, b_prv, mupF, varpF, lane, wv);
  __syncthreads();

  pstage_add(hC, wt, PO1H_T, Pbuf, row0, X1, lane, wv);
  __syncthreads();
  stage256(X1, wt, PO2_T, b_po2, X2, lane, wv);
  __syncthreads();
  pheads(X2, wt, POM_T, POV_T, b_pom, b_pov, muqF, varqF, lane, wv);
  __syncthreads();

  {
    int r = wv;
    float kv = 0.f;
    #pragma unroll
    for (int ii = 0; ii < 2; ii++){
      int c = lane + ii*64;
      float mq = muqF[r*LATN + c], vq = varqF[r*LATN + c];
      float mp = mupF[r*LATN + c], vp = varpF[r*LATN + c];
      float d = mq - mp;
      kv += __logf(vp) - __logf(vq) + (vq + d*d)/vp - 1.f;
    }
    #pragma unroll
    for (int m = 1; m < 64; m <<= 1) kv += __shfl_xor(kv, m, 64);
    if (lane == 0)
      __builtin_nontemporal_store(0.5f*kv, &out[KL_OFF + (size_t)(row0 + r)]);
  }
}

// ---------------------------------------------------------------------------
extern "C" void kernel_launch(void* const* d_in, const int* in_sizes, int n_in,
                              void* d_out, int out_size, void* d_ws, size_t ws_size,
                              hipStream_t stream)
{
  (void)in_sizes; (void)n_in; (void)out_size; (void)ws_size;
  const float* vis    = (const float*)d_in[0];
  const float* acts   = (const float*)d_in[1];
  const float* noise  = (const float*)d_in[2];
  const float* w_obs1 = (const float*)d_in[3];
  const float* b_obs1 = (const float*)d_in[4];
  const float* w_obs2 = (const float*)d_in[5];
  const float* b_obs2 = (const float*)d_in[6];
  const float* w_gin  = (const float*)d_in[7];
  const float* b_gin  = (const float*)d_in[8];
  const float* w_ih   = (const float*)d_in[9];
  const float* w_hh   = (const float*)d_in[10];
  const float* b_ih   = (const float*)d_in[11];
  const float* b_hh   = (const float*)d_in[12];
  const float* w_pr1  = (const float*)d_in[13];
  const float* b_pr1  = (const float*)d_in[14];
  const float* w_pr2  = (const float*)d_in[15];
  const float* b_pr2  = (const float*)d_in[16];
  const float* w_prm  = (const float*)d_in[17];
  const float* b_prm  = (const float*)d_in[18];
  const float* w_prv  = (const float*)d_in[19];
  const float* b_prv  = (const float*)d_in[20];
  const float* w_po1  = (const float*)d_in[21];
  const float* b_po1  = (const float*)d_in[22];
  const float* w_po2  = (const float*)d_in[23];
  const float* b_po2  = (const float*)d_in[24];
  const float* w_pom  = (const float*)d_in[25];
  const float* b_pom  = (const float*)d_in[26];
  const float* w_pov  = (const float*)d_in[27];
  const float* b_pov  = (const float*)d_in[28];

  unsigned short* B1 = (unsigned short*)d_ws;                       // 65536x256 bf16
  unsigned short* WT = (unsigned short*)((char*)d_ws + B1_BYTES);   // shuffled tiles
  unsigned short* Hb  = WT + (size_t)TOT_TILES*512;                 // h_t (B*127 x 256)
  unsigned short* XH  = Hb + (size_t)BN*127*256;                    // h parity slices
  unsigned*       CNT = (unsigned*)(XH + (size_t)2*32*8*512);       // 32 counters

  ShufArgs sa;
  const float* srcs[14] = {w_obs1, w_obs2, w_po1, w_po1, w_gin, w_ih, w_hh,
                           w_pr1, w_pr2, w_prm, w_prv, w_po2, w_pom, w_pov};
  const int strides[14] = {512,256,512,512,136,256,256,256,256,256,256,256,256,256};
  const int coloffs[14] = {0,0,256,0,0,0,0,0,0,0,0,0,0,0};
  const int ktl[14]     = {16,8,8,8,4,8,8,8,8,8,8,8,8,8};
  const int tbas[14]    = {OBS1_T,OBS2_T,PO1O_T,PO1H_T,GINS_T,IH_T,HH_T,
                           PR1_T,PR2_T,PRM_T,PRV_T,PO2_T,POM_T,POV_T};
  const int tcnt[14]    = {256,128,128,128,64,384,384,128,128,64,64,128,64,64};
  for (int i = 0; i < 14; i++){
    sa.src[i] = srcs[i]; sa.stride[i] = strides[i]; sa.coloff[i] = coloffs[i];
    sa.ktiles[i] = ktl[i]; sa.tbase[i] = tbas[i]; sa.tcnt[i] = tcnt[i];
  }
  shuffle_w<<<TOT_TILES, 64, 0, stream>>>(sa, WT);

  // obs MLP + po1_o, all in-place in B1 (rows are block-exclusive)
  big_gemm<<<1024, 256, 0, stream>>>(vis, 1, 512, WT, OBS1_T, b_obs1, 1, B1);
  big_gemm<<<1024, 256, 0, stream>>>(B1,  0, 256, WT, OBS2_T, b_obs2, 1, B1);
  big_gemm<<<1024, 256, 0, stream>>>(B1,  0, 256, WT, PO1O_T, b_po1,  0, B1);

  // zero H parity buffers + barrier counters (replayed each graph run)
  hipMemsetAsync(XH, 0, (size_t)2*32*8*512*2, stream);
  hipMemsetAsync(CNT, 0, 32*4, stream);

  RnnArgs ra;
  ra.wt = WT; ra.Pbuf = B1;
  ra.actions = acts; ra.noise = noise; ra.w_gin = w_gin;
  ra.b_gin = b_gin; ra.b_ih = b_ih; ra.b_hh = b_hh;
  ra.b_po2 = b_po2; ra.b_pom = b_pom; ra.b_pov = b_pov;
  ra.Hb = Hb; ra.XH = XH; ra.cnt = CNT; ra.out = (float*)d_out;
  rssm_rnn<<<256, 128, 0, stream>>>(ra);

  post_pass<<<4064, 1024, 0, stream>>>(WT, B1, Hb, b_pr1, b_pr2, b_prm, b_prv,
                                       b_po2, b_pom, b_pov, (float*)d_out);
}

// Round 7
// 4311.382 us; speedup vs baseline: 1.2449x; 1.2449x over previous
//
#include <hip/hip_runtime.h>
#include <math.h>

// ============================================================================
// RSSM forward on MI355X.
// Round 10: R7 structure (best: rnn 1434us) + XCD-local sync fast path.
// R9 post-mortem: replicated stages -> VGPR 256 + scratch spills (WRITE_SIZE
// 598MB) + 8-way LDS conflicts (1.6e8) -> 2x regression. Reverted.
// R7's step = 5 x 2.26us agent-scope (MALL round-trip) sync segments. A
// group's 8 members (blockIdx = g + 32j) share blockIdx%8 -> one XCD -> one
// shared L2. Same-XCD exchange can use the L2 as coherence point: plain
// write-through stores + volatile (sc0, L1-bypass) loads + workgroup-scope
// global atomics (execute at L2) -> ~5x cheaper RT. Mapping is verified at
// runtime (s_getreg HW_REG_XCC_ID published per block, agent-scope init
// barrier, all-equal-within-group + neighbor-groups-differ sanity check);
// on failure falls back to the proven R7 agent-scope path bit-for-bit.
// Fast/slow flag counters in disjoint 256B-padded regions (no cross-XCD
// line sharing). Exchange data, tile order, rounding identical to R7.
// ============================================================================

using v8s   = __attribute__((ext_vector_type(8))) short;
using f32x4 = __attribute__((ext_vector_type(4))) float;
typedef unsigned long long u64;

#define BN   512
#define TN   128
#define LATN 128

#define AB_S 264   // 256-col LDS activation stride (shorts)
#define SA_S 136

// pre-shuffled weight tile bases (1 tile = 16n x 32k bf16 = 1KB = 512 shorts)
#define OBS1_T 0
#define OBS2_T 256
#define PO1O_T 384
#define PO1H_T 512
#define GINS_T 640
#define IH_T   704
#define HH_T   1088
#define PR1_T  1472
#define PR2_T  1600
#define PRM_T  1728
#define PRV_T  1792
#define PO2_T  1856
#define POM_T  1984
#define POV_T  2048
#define TOT_TILES 2112

#define B1_BYTES 33554432UL          // 65536 x 256 bf16
#define KL_OFF   8388608UL           // states elements (512*128*128)

// local (LDS) tile bases for the rnn weight slices
#define GIN_L 0     // 8 tiles
#define IH_L  8     // 48
#define HH_L  56    // 48
#define P1_L  104   // 16
#define P2_L  120   // 16
#define NLT   136

__device__ __forceinline__ unsigned short f2bf(float f){
  union { float f; unsigned u; } v; v.f = f;
  unsigned u = v.u + 0x7fffu + ((v.u >> 16) & 1u);   // RNE
  return (unsigned short)(u >> 16);
}
__device__ __forceinline__ float bf2f(unsigned short s){
  union { unsigned u; float f; } v; v.u = ((unsigned)s) << 16; return v.f;
}
__device__ __forceinline__ float sigm(float x){ return 1.f / (1.f + __expf(-x)); }
__device__ __forceinline__ float tanhx(float x){ return 1.f - 2.f/(__expf(2.f*x) + 1.f); }

#define MFMA16(a,b,c) __builtin_amdgcn_mfma_f32_16x16x32_bf16((a),(b),(c),0,0,0)
#define LDB(tIdx) (*(const v8s*)(wt + ((size_t)(tIdx))*512 + lane*8))

// HW_REG_XCC_ID = hwreg 20 on gfx940+/gfx950
__device__ __forceinline__ unsigned getXcc(){
  unsigned x;
  asm volatile("s_getreg_b32 %0, hwreg(20, 0, 32)" : "=s"(x));
  return x & 0xffu;
}

// ---------------------------------------------------------------------------
// Exchange primitives.
// fast (same-XCD, runtime-verified): plain write-through stores + volatile
//   (sc0, L1-bypass) loads -- coherence point is the shared per-XCD L2.
// slow (fallback): relaxed agent-scope atomics -- coherence point is MALL.
// ---------------------------------------------------------------------------
__device__ __forceinline__ void stxs(unsigned short* p, unsigned short v, bool fast){
  if (fast) *(volatile unsigned short*)p = v;
  else      __hip_atomic_store(p, v, __ATOMIC_RELAXED, __HIP_MEMORY_SCOPE_AGENT);
}
__device__ __forceinline__ v8s ldx16(const unsigned short* p, bool fast){
  union { u64 u[2]; v8s v; } x;
  if (fast){
    x.u[0] = *(volatile const u64*)p;
    x.u[1] = *((volatile const u64*)p + 1);
  } else {
    x.u[0] = __hip_atomic_load((u64*)p,     __ATOMIC_RELAXED, __HIP_MEMORY_SCOPE_AGENT);
    x.u[1] = __hip_atomic_load((u64*)p + 1, __ATOMIC_RELAXED, __HIP_MEMORY_SCOPE_AGENT);
  }
  return x.v;
}

// ---------------------------------------------------------------------------
// Weight shuffle: f32 (N,K) row-major -> bf16 fragment-linear tiles.
// ---------------------------------------------------------------------------
struct ShufArgs {
  const float* src[14];
  int stride[14], coloff[14], ktiles[14], tbase[14], tcnt[14];
};

__global__ __launch_bounds__(64) void shuffle_w(ShufArgs sa, unsigned short* __restrict__ wt)
{
  int tile = blockIdx.x;
  int s = 0;
  while (tile >= sa.tbase[s] + sa.tcnt[s]) s++;
  int lt = tile - sa.tbase[s];
  int kt = lt % sa.ktiles[s];
  int nt = lt / sa.ktiles[s];
  int l  = threadIdx.x;
  int n  = nt*16 + (l & 15);
  int k  = sa.coloff[s] + kt*32 + (l >> 4)*8;
  const float* sp = sa.src[s] + (size_t)n * sa.stride[s] + k;
  unsigned short* dp = wt + (size_t)tile*512 + (size_t)l*8;
  #pragma unroll
  for (int j = 0; j < 8; j++) dp[j] = f2bf(sp[j]);
}

// ---------------------------------------------------------------------------
// Parallel GEMM for obs MLP / po1_o precompute.
// ---------------------------------------------------------------------------
__global__ __launch_bounds__(256) void big_gemm(
    const void* __restrict__ Ain, int aIsF32, int K,
    const unsigned short* __restrict__ wt, int tbase,
    const float* __restrict__ bias, int doRelu,
    unsigned short* __restrict__ outB)
{
  __shared__ unsigned short AL[64*AB_S];
  int tid = threadIdx.x, lane = tid & 63, wv = tid >> 6;
  int q = lane >> 4, c16 = lane & 15;
  size_t row0 = (size_t)blockIdx.x * 64;

  f32x4 acc[16];
  #pragma unroll
  for (int nt = 0; nt < 16; nt++) acc[nt] = (f32x4){0.f,0.f,0.f,0.f};

  int nchunk = K >> 8;
  int ktT    = K >> 5;
  for (int cc = 0; cc < nchunk; cc++){
    int r = tid >> 2, c0 = (tid & 3) * 64;
    if (aIsF32){
      const float* A = (const float*)Ain + (row0 + r) * (size_t)K + (size_t)cc*256 + c0;
      #pragma unroll
      for (int ii = 0; ii < 16; ii++){
        float4 x = ((const float4*)A)[ii];
        ushort4 o;
        o.x = f2bf(x.x); o.y = f2bf(x.y); o.z = f2bf(x.z); o.w = f2bf(x.w);
        *(ushort4*)&AL[r*AB_S + c0 + ii*4] = o;
      }
    } else {
      const unsigned short* A = (const unsigned short*)Ain + (row0 + r)*256 + c0;
      #pragma unroll
      for (int ii = 0; ii < 8; ii++)
        *(v8s*)&AL[r*AB_S + c0 + ii*8] = *(const v8s*)(A + ii*8);
    }
    __syncthreads();
    const unsigned short* myA = &AL[wv*16*AB_S];
    #pragma unroll
    for (int kt = 0; kt < 8; kt++){
      v8s af = *(const v8s*)&myA[c16*AB_S + kt*32 + q*8];
      #pragma unroll
      for (int nt = 0; nt < 16; nt++){
        v8s bf = *(const v8s*)(wt + ((size_t)(tbase + nt*ktT + cc*8 + kt))*512 + lane*8);
        acc[nt] = MFMA16(af, bf, acc[nt]);
      }
    }
    __syncthreads();
  }
  #pragma unroll
  for (int nt = 0; nt < 16; nt++){
    int col = nt*16 + c16;
    float b = bias[col];
    #pragma unroll
    for (int i = 0; i < 4; i++){
      float v = acc[nt][i] + b;
      if (doRelu) v = fmaxf(v, 0.f);
      outB[(row0 + wv*16 + q*4 + i)*256 + col] = f2bf(v);
    }
  }
}

// ---------------------------------------------------------------------------
// post_pass helpers (16 rows x 256 cols, 16 waves; wave wv owns nt = wv).
// ---------------------------------------------------------------------------
__device__ __forceinline__ void stage256(
    const unsigned short* __restrict__ inA,
    const unsigned short* __restrict__ wt, int tbase,
    const float* __restrict__ bias,
    unsigned short* __restrict__ outA, int lane, int wv)
{
  int q = lane >> 4, c16 = lane & 15;
  v8s wf[8];
  #pragma unroll
  for (int kt = 0; kt < 8; kt++) wf[kt] = LDB(tbase + wv*8 + kt);
  v8s af[8];
  #pragma unroll
  for (int kt = 0; kt < 8; kt++) af[kt] = *(const v8s*)&inA[c16*AB_S + kt*32 + q*8];
  f32x4 acc = (f32x4){0.f,0.f,0.f,0.f};
  #pragma unroll
  for (int kt = 0; kt < 8; kt++) acc = MFMA16(af[kt], wf[kt], acc);
  int col = wv*16 + c16;
  float b = bias[col];
  #pragma unroll
  for (int i = 0; i < 4; i++)
    outA[(q*4 + i)*AB_S + col] = f2bf(fmaxf(acc[i] + b, 0.f));
}

__device__ __forceinline__ void pheads(
    const unsigned short* __restrict__ X2,
    const unsigned short* __restrict__ wt, int tM, int tV,
    const float* __restrict__ bM, const float* __restrict__ bV,
    float* __restrict__ muF, float* __restrict__ varF, int lane, int wv)
{
  int q = lane >> 4, c16 = lane & 15;
  int mtx = wv >> 3, nt = wv & 7;
  int tb  = mtx ? tV : tM;
  v8s wf[8];
  #pragma unroll
  for (int kt = 0; kt < 8; kt++) wf[kt] = LDB(tb + nt*8 + kt);
  v8s af[8];
  #pragma unroll
  for (int kt = 0; kt < 8; kt++) af[kt] = *(const v8s*)&X2[c16*AB_S + kt*32 + q*8];
  f32x4 acc = (f32x4){0.f,0.f,0.f,0.f};
  #pragma unroll
  for (int kt = 0; kt < 8; kt++) acc = MFMA16(af[kt], wf[kt], acc);
  int col = nt*16 + c16;
  float b = mtx ? bV[col] : bM[col];
  float* dst = mtx ? varF : muF;
  #pragma unroll
  for (int i = 0; i < 4; i++){
    float v = acc[i] + b;
    if (mtx) v = __expf(v) + 0.01f;
    dst[(q*4 + i)*LATN + col] = v;
  }
}

__device__ __forceinline__ void pstage_add(
    const unsigned short* __restrict__ inA,
    const unsigned short* __restrict__ wt, int tbase,
    const unsigned short* __restrict__ Pbuf, int row0,
    unsigned short* __restrict__ outA, int lane, int wv)
{
  int q = lane >> 4, c16 = lane & 15;
  v8s wf[8];
  #pragma unroll
  for (int kt = 0; kt < 8; kt++) wf[kt] = LDB(tbase + wv*8 + kt);
  v8s af[8];
  #pragma unroll
  for (int kt = 0; kt < 8; kt++) af[kt] = *(const v8s*)&inA[c16*AB_S + kt*32 + q*8];
  int col = wv*16 + c16;
  unsigned short pv[4];
  #pragma unroll
  for (int i = 0; i < 4; i++){
    int grow = row0 + q*4 + i;          // = b*127 + t
    int prow = grow + grow/127 + 1;     // = b*128 + (t+1)
    pv[i] = __builtin_nontemporal_load(&Pbuf[(size_t)prow*256 + col]);
  }
  f32x4 acc = (f32x4){0.f,0.f,0.f,0.f};
  #pragma unroll
  for (int kt = 0; kt < 8; kt++) acc = MFMA16(af[kt], wf[kt], acc);
  #pragma unroll
  for (int i = 0; i < 4; i++){
    float v = acc[i] + bf2f(pv[i]);
    outA[(q*4 + i)*AB_S + col] = f2bf(fmaxf(v, 0.f));
  }
}

// ---------------------------------------------------------------------------
// Group barrier: central monotonic epoch counter.
// fast: workgroup-scope fetch_add (executes in the shared per-XCD L2) +
//       volatile poll (sc0, hits the same L2). Safe only because the same-XCD
//       property was runtime-verified.
// slow: R7-proven relaxed agent-scope RMW/poll at MALL.
// __syncthreads' vmcnt(0) drain puts the exchange stores at the coherence
// point before tid0's add issues.
// ---------------------------------------------------------------------------
__device__ __forceinline__ void gsync(unsigned* c, unsigned tgt, int tid, bool fast)
{
  __syncthreads();
  asm volatile("" ::: "memory");
  if (tid == 0){
    if (fast){
      __hip_atomic_fetch_add(c, 1u, __ATOMIC_RELAXED, __HIP_MEMORY_SCOPE_WORKGROUP);
      while (*(volatile unsigned*)c < tgt)
        __builtin_amdgcn_s_sleep(1);
    } else {
      __hip_atomic_fetch_add(c, 1u, __ATOMIC_RELAXED, __HIP_MEMORY_SCOPE_AGENT);
      while (__hip_atomic_load(c, __ATOMIC_RELAXED, __HIP_MEMORY_SCOPE_AGENT) < tgt)
        __builtin_amdgcn_s_sleep(1);
    }
  }
  asm volatile("" ::: "memory");
  __syncthreads();
}

// ---------------------------------------------------------------------------
// Distributed recurrence (R7 structure). Grid 256 = 32 groups x 8 members;
// group g handles batch rows g*16..g*16+15; member j owns output cols
// [32j,32j+32) of every 256-wide stage and latent cols [16j,16j+16) of the
// heads. 128 threads = 2 waves; wave wv owns ntile 2j+wv.
// ---------------------------------------------------------------------------
struct RnnArgs {
  const unsigned short *wt, *Pbuf;
  const float *actions, *noise, *w_gin, *b_gin, *b_ih, *b_hh, *b_po2, *b_pom, *b_pov;
  unsigned short *Hb, *XS, *XG, *XH, *XM1, *XM2;
  unsigned *cnt;     // agent counters: [g*16+ph] slow phases, [512+g] init
  unsigned *fcnt;    // fast counters:  [g*64+ph], 256B per group
  unsigned *xcc;     // per-block XCC_ID publish area [256]
  float *out;
};

__global__ __launch_bounds__(128, 1) void rssm_rnn(RnnArgs A)
{
  __shared__ unsigned short Lw[NLT*512];     // 139264 B weight slices
  __shared__ float LwaA[256];                // w_gin action part [32 cols][8]
  __shared__ float Lbg[32], Lbih[96], Lbhh[96], Lbp2[32], Lbm[16], Lbv[16];
  __shared__ float muv[2][16][16];
  __shared__ float aF[128];

  int tid = threadIdx.x, lane = tid & 63, wv = tid >> 6;
  int q = lane >> 4, c16 = lane & 15;
  int g = blockIdx.x & 31, j = blockIdx.x >> 5;
  int b0 = g * 16;
  int lc = wv*16 + c16;          // local col in the 32-wide slice
  int gc = 32*j + lc;            // global col

  // ---- pin weight slices in LDS ----
  for (int u = tid; u < NLT*64; u += 128){
    int lt = u >> 6, ch = u & 63;
    int gt;
    if (lt < 8){
      int w = lt >> 2, kt = lt & 3;
      gt = GINS_T + (2*j + w)*4 + kt;
    } else if (lt < 56){
      int u2 = lt - 8;
      gt = IH_T + ((u2 >> 4)*16 + 2*j + ((u2 >> 3) & 1))*8 + (u2 & 7);
    } else if (lt < 104){
      int u2 = lt - 56;
      gt = HH_T + ((u2 >> 4)*16 + 2*j + ((u2 >> 3) & 1))*8 + (u2 & 7);
    } else if (lt < 120){
      int u2 = lt - 104;
      gt = PO1H_T + (2*j + (u2 >> 3))*8 + (u2 & 7);
    } else {
      int u2 = lt - 120;
      gt = PO2_T + (2*j + (u2 >> 3))*8 + (u2 & 7);
    }
    *(v8s*)&Lw[lt*512 + ch*8] = *(const v8s*)(A.wt + (size_t)gt*512 + ch*8);
  }
  for (int u = tid; u < 256; u += 128)
    LwaA[u] = A.w_gin[(size_t)(32*j + (u >> 3))*136 + 128 + (u & 7)];
  if (tid < 32){ Lbg[tid] = A.b_gin[32*j + tid]; Lbp2[tid] = A.b_po2[32*j + tid]; }
  if (tid >= 32 && tid < 128){
    int u = tid - 32;
    if (u < 96){
      Lbih[u] = A.b_ih[(u >> 5)*256 + 32*j + (u & 31)];
      Lbhh[u] = A.b_hh[(u >> 5)*256 + 32*j + (u & 31)];
    }
  }
  if (tid < 16){ Lbm[tid] = A.b_pom[16*j + tid]; Lbv[tid] = A.b_pov[16*j + tid]; }

  v8s wh[8];   // head weights persistent in registers (wave0: pom, wave1: pov)
  {
    const unsigned short* wt = A.wt;
    int tb = (wv ? POV_T : POM_T) + j*8;
    #pragma unroll
    for (int kt = 0; kt < 8; kt++) wh[kt] = LDB(tb + kt);
  }
  float hFr[4] = {0.f, 0.f, 0.f, 0.f};   // f32 h carry, rows q*4+i, col gc

  // ---- publish XCC_ID, init barrier (agent scope), decide fast/slow ----
  if (tid == 0)
    __hip_atomic_store(A.xcc + blockIdx.x, getXcc(),
                       __ATOMIC_RELAXED, __HIP_MEMORY_SCOPE_AGENT);
  gsync(A.cnt + 512 + g, 8u, tid, false);
  bool fast;
  {
    unsigned x0 = __hip_atomic_load(A.xcc + g, __ATOMIC_RELAXED, __HIP_MEMORY_SCOPE_AGENT);
    bool eq = true;
    #pragma unroll
    for (int u = 1; u < 8; u++)
      eq &= (__hip_atomic_load(A.xcc + g + 32*u, __ATOMIC_RELAXED,
                               __HIP_MEMORY_SCOPE_AGENT) == x0);
    // sanity: a real %8 mapping puts neighbor groups on different XCDs; a
    // broken/constant s_getreg would make everything equal -> force slow.
    unsigned xn = __hip_atomic_load(A.xcc + ((g + 1) & 31), __ATOMIC_RELAXED,
                                    __HIP_MEMORY_SCOPE_AGENT);
    fast = eq && (xn != x0);
  }
  __syncthreads();

  unsigned* cS  = (fast ? A.fcnt + g*64 + 0 : A.cnt + g*16 + 0);
  unsigned* cG  = (fast ? A.fcnt + g*64 + 1 : A.cnt + g*16 + 1);
  unsigned* cH  = (fast ? A.fcnt + g*64 + 2 : A.cnt + g*16 + 2);
  unsigned* cM1 = (fast ? A.fcnt + g*64 + 3 : A.cnt + g*16 + 3);
  unsigned* cM2 = (fast ? A.fcnt + g*64 + 4 : A.cnt + g*16 + 4);
  const size_t sl = (size_t)(g*8);   // slice index base for this group

  for (int t = -1; t < TN-1; t++){
    unsigned e2 = (unsigned)(8*(t+2));
    if (t >= 0){
      aF[tid] = __builtin_nontemporal_load(
          &A.actions[((size_t)(b0 + (tid >> 3))*127 + t)*8 + (tid & 7)]);
      __syncthreads();
      // ---- gin: g = relu(s @ WginS^T + a @ WginA^T + b_gin) ----
      {
        v8s af4[4], wf[4];
        #pragma unroll
        for (int kt = 0; kt < 4; kt++)
          af4[kt] = ldx16(A.XS + ((sl + 2*kt + (q >> 1))*16 + c16)*16 + (q & 1)*8, fast);
        #pragma unroll
        for (int kt = 0; kt < 4; kt++)
          wf[kt] = *(const v8s*)&Lw[(GIN_L + wv*4 + kt)*512 + lane*8];
        f32x4 acc = (f32x4){0.f,0.f,0.f,0.f};
        #pragma unroll
        for (int kt = 0; kt < 4; kt++) acc = MFMA16(af4[kt], wf[kt], acc);
        float bg = Lbg[lc];
        #pragma unroll
        for (int i = 0; i < 4; i++){
          int r = q*4 + i;
          float v = acc[i] + bg;
          #pragma unroll
          for (int m = 0; m < 8; m++) v += aF[r*8 + m]*LwaA[lc*8 + m];
          stxs(&A.XG[((sl + j)*16 + r)*32 + lc], f2bf(fmaxf(v, 0.f)), fast);
        }
      }
      gsync(cG, (unsigned)(8*(t+1)), tid, fast);
      // ---- GRU ----
      {
        int p = t & 1;
        v8s ag[8], ah[8];
        #pragma unroll
        for (int kt = 0; kt < 8; kt++){
          ag[kt] = ldx16(A.XG + ((sl + kt)*16 + c16)*32 + q*8, fast);
          ah[kt] = ldx16(A.XH + (((size_t)p*256 + sl + kt)*16 + c16)*32 + q*8, fast);
        }
        f32x4 accI[3];
        #pragma unroll
        for (int x = 0; x < 3; x++){
          v8s wf[8];
          #pragma unroll
          for (int kt = 0; kt < 8; kt++)
            wf[kt] = *(const v8s*)&Lw[(IH_L + (x*2 + wv)*8 + kt)*512 + lane*8];
          accI[x] = (f32x4){0.f,0.f,0.f,0.f};
          #pragma unroll
          for (int kt = 0; kt < 8; kt++) accI[x] = MFMA16(ag[kt], wf[kt], accI[x]);
        }
        float rg[4], zg[4];
        {
          v8s wf[8];
          #pragma unroll
          for (int kt = 0; kt < 8; kt++)
            wf[kt] = *(const v8s*)&Lw[(HH_L + (0*2 + wv)*8 + kt)*512 + lane*8];
          f32x4 a = (f32x4){0.f,0.f,0.f,0.f};
          #pragma unroll
          for (int kt = 0; kt < 8; kt++) a = MFMA16(ah[kt], wf[kt], a);
          float bir = Lbih[lc], bhr = Lbhh[lc];
          #pragma unroll
          for (int i = 0; i < 4; i++) rg[i] = sigm(accI[0][i] + bir + a[i] + bhr);
        }
        {
          v8s wf[8];
          #pragma unroll
          for (int kt = 0; kt < 8; kt++)
            wf[kt] = *(const v8s*)&Lw[(HH_L + (1*2 + wv)*8 + kt)*512 + lane*8];
          f32x4 a = (f32x4){0.f,0.f,0.f,0.f};
          #pragma unroll
          for (int kt = 0; kt < 8; kt++) a = MFMA16(ah[kt], wf[kt], a);
          float biz = Lbih[32 + lc], bhz = Lbhh[32 + lc];
          #pragma unroll
          for (int i = 0; i < 4; i++) zg[i] = sigm(accI[1][i] + biz + a[i] + bhz);
        }
        {
          v8s wf[8];
          #pragma unroll
          for (int kt = 0; kt < 8; kt++)
            wf[kt] = *(const v8s*)&Lw[(HH_L + (2*2 + wv)*8 + kt)*512 + lane*8];
          f32x4 a = (f32x4){0.f,0.f,0.f,0.f};
          #pragma unroll
          for (int kt = 0; kt < 8; kt++) a = MFMA16(ah[kt], wf[kt], a);
          float bin = Lbih[64 + lc], bhn = Lbhh[64 + lc];
          #pragma unroll
          for (int i = 0; i < 4; i++){
            int r = q*4 + i;
            float ng = tanhx(accI[2][i] + bin + rg[i]*(a[i] + bhn));
            float hv = (1.f - zg[i])*ng + zg[i]*hFr[i];
            hFr[i] = hv;
            unsigned short hb = f2bf(hv);
            stxs(&A.XH[(((size_t)(1 - p)*256 + sl + j)*16 + r)*32 + lc], hb, fast);
            __builtin_nontemporal_store(hb, &A.Hb[((size_t)(b0 + r)*127 + t)*256 + gc]);
          }
        }
      }
      // hoist: pv from Pbuf (read-only, no barrier dependency)
      unsigned short pv[4];
      #pragma unroll
      for (int i = 0; i < 4; i++)
        pv[i] = __builtin_nontemporal_load(
            &A.Pbuf[((size_t)(b0 + q*4 + i)*TN + (t+1))*256 + gc]);
      gsync(cH, (unsigned)(8*(t+1)), tid, fast);
      // ---- po1h -> m1 ----
      {
        int p = t & 1;
        v8s ah2[8], wf[8];
        #pragma unroll
        for (int kt = 0; kt < 8; kt++)
          ah2[kt] = ldx16(A.XH + (((size_t)(1 - p)*256 + sl + kt)*16 + c16)*32 + q*8, fast);
        #pragma unroll
        for (int kt = 0; kt < 8; kt++)
          wf[kt] = *(const v8s*)&Lw[(P1_L + wv*8 + kt)*512 + lane*8];
        f32x4 acc = (f32x4){0.f,0.f,0.f,0.f};
        #pragma unroll
        for (int kt = 0; kt < 8; kt++) acc = MFMA16(ah2[kt], wf[kt], acc);
        #pragma unroll
        for (int i = 0; i < 4; i++)
          stxs(&A.XM1[((sl + j)*16 + q*4 + i)*32 + lc],
               f2bf(fmaxf(acc[i] + bf2f(pv[i]), 0.f)), fast);
      }
    } else {
      // ---- prologue: m1 = relu(po1_o[:, t=0]) (belief = 0) ----
      #pragma unroll
      for (int i = 0; i < 4; i++){
        int r = q*4 + i;
        unsigned short pv0 = __builtin_nontemporal_load(
            &A.Pbuf[((size_t)(b0 + r)*TN + 0)*256 + gc]);
        stxs(&A.XM1[((sl + j)*16 + r)*32 + lc], f2bf(fmaxf(bf2f(pv0), 0.f)), fast);
      }
    }
    gsync(cM1, e2, tid, fast);
    // ---- po2 -> m2 ----
    {
      v8s am[8], wf[8];
      #pragma unroll
      for (int kt = 0; kt < 8; kt++)
        am[kt] = ldx16(A.XM1 + ((sl + kt)*16 + c16)*32 + q*8, fast);
      #pragma unroll
      for (int kt = 0; kt < 8; kt++)
        wf[kt] = *(const v8s*)&Lw[(P2_L + wv*8 + kt)*512 + lane*8];
      f32x4 acc = (f32x4){0.f,0.f,0.f,0.f};
      #pragma unroll
      for (int kt = 0; kt < 8; kt++) acc = MFMA16(am[kt], wf[kt], acc);
      #pragma unroll
      for (int i = 0; i < 4; i++)
        stxs(&A.XM2[((sl + j)*16 + q*4 + i)*32 + lc],
             f2bf(fmaxf(acc[i] + Lbp2[lc], 0.f)), fast);
    }
    gsync(cM2, e2, tid, fast);
    // ---- heads (wave0: mu, wave1: var) ----
    {
      v8s am[8];
      #pragma unroll
      for (int kt = 0; kt < 8; kt++)
        am[kt] = ldx16(A.XM2 + ((sl + kt)*16 + c16)*32 + q*8, fast);
      f32x4 acc = (f32x4){0.f,0.f,0.f,0.f};
      #pragma unroll
      for (int kt = 0; kt < 8; kt++) acc = MFMA16(am[kt], wh[kt], acc);
      #pragma unroll
      for (int i = 0; i < 4; i++){
        float v = acc[i] + (wv ? Lbv[c16] : Lbm[c16]);
        if (wv) v = __expf(v) + 0.01f;
        muv[wv][q*4 + i][c16] = v;
      }
    }
    __syncthreads();
    // ---- sample: s = mu + sqrt(var)*eps ----
    for (int u = tid; u < 256; u += 128){
      int r = u >> 4, c = u & 15;
      float mq = muv[0][r][c], vq = muv[1][r][c];
      float ep = __builtin_nontemporal_load(
          &A.noise[((size_t)(t+1)*BN + b0 + r)*LATN + 16*j + c]);
      float sv = mq + sqrtf(vq)*ep;
      __builtin_nontemporal_store(sv, &A.out[((size_t)(b0 + r)*TN + (t+1))*LATN + 16*j + c]);
      stxs(&A.XS[(sl + j)*256 + r*16 + c], f2bf(sv), fast);
    }
    gsync(cS, e2, tid, fast);
  }
}

// ---------------------------------------------------------------------------
// Parallel post-pass over all (b,t) rows: prior + posterior + KL.
// ---------------------------------------------------------------------------
__global__ __launch_bounds__(1024, 4) void post_pass(
    const unsigned short* __restrict__ wt,
    const unsigned short* __restrict__ Pbuf,
    const unsigned short* __restrict__ Hb,
    const float* __restrict__ b_pr1, const float* __restrict__ b_pr2,
    const float* __restrict__ b_prm, const float* __restrict__ b_prv,
    const float* __restrict__ b_po2, const float* __restrict__ b_pom,
    const float* __restrict__ b_pov,
    float* __restrict__ out)
{
  __shared__ unsigned short hC[16*AB_S];
  __shared__ unsigned short X1[16*AB_S];
  __shared__ unsigned short X2[16*AB_S];
  __shared__ float mupF[16*LATN], varpF[16*LATN];
  __shared__ float muqF[16*LATN], varqF[16*LATN];

  int tid = threadIdx.x, lane = tid & 63, wv = tid >> 6;
  int row0 = blockIdx.x * 16;

  if (tid < 512){
    int r = tid >> 5, c8 = (tid & 31)*8;
    *(v8s*)&hC[r*AB_S + c8] = *(const v8s*)&Hb[(size_t)(row0 + r)*256 + c8];
  }
  __syncthreads();

  stage256(hC, wt, PR1_T, b_pr1, X1, lane, wv);
  __syncthreads();
  stage256(X1, wt, PR2_T, b_pr2, X2, lane, wv);
  __syncthreads();
  pheads(X2, wt, PRM_T, PRV_T, b_prm, b_prv, mupF, varpF, lane, wv);
  __syncthreads();

  pstage_add(hC, wt, PO1H_T, Pbuf, row0, X1, lane, wv);
  __syncthreads();
  stage256(X1, wt, PO2_T, b_po2, X2, lane, wv);
  __syncthreads();
  pheads(X2, wt, POM_T, POV_T, b_pom, b_pov, muqF, varqF, lane, wv);
  __syncthreads();

  {
    int r = wv;
    float kv = 0.f;
    #pragma unroll
    for (int ii = 0; ii < 2; ii++){
      int c = lane + ii*64;
      float mq = muqF[r*LATN + c], vq = varqF[r*LATN + c];
      float mp = mupF[r*LATN + c], vp = varpF[r*LATN + c];
      float d = mq - mp;
      kv += __logf(vp) - __logf(vq) + (vq + d*d)/vp - 1.f;
    }
    #pragma unroll
    for (int m = 1; m < 64; m <<= 1) kv += __shfl_xor(kv, m, 64);
    if (lane == 0)
      __builtin_nontemporal_store(0.5f*kv, &out[KL_OFF + (size_t)(row0 + r)]);
  }
}

// ---------------------------------------------------------------------------
extern "C" void kernel_launch(void* const* d_in, const int* in_sizes, int n_in,
                              void* d_out, int out_size, void* d_ws, size_t ws_size,
                              hipStream_t stream)
{
  (void)in_sizes; (void)n_in; (void)out_size; (void)ws_size;
  const float* vis    = (const float*)d_in[0];
  const float* acts   = (const float*)d_in[1];
  const float* noise  = (const float*)d_in[2];
  const float* w_obs1 = (const float*)d_in[3];
  const float* b_obs1 = (const float*)d_in[4];
  const float* w_obs2 = (const float*)d_in[5];
  const float* b_obs2 = (const float*)d_in[6];
  const float* w_gin  = (const float*)d_in[7];
  const float* b_gin  = (const float*)d_in[8];
  const float* w_ih   = (const float*)d_in[9];
  const float* w_hh   = (const float*)d_in[10];
  const float* b_ih   = (const float*)d_in[11];
  const float* b_hh   = (const float*)d_in[12];
  const float* w_pr1  = (const float*)d_in[13];
  const float* b_pr1  = (const float*)d_in[14];
  const float* w_pr2  = (const float*)d_in[15];
  const float* b_pr2  = (const float*)d_in[16];
  const float* w_prm  = (const float*)d_in[17];
  const float* b_prm  = (const float*)d_in[18];
  const float* w_prv  = (const float*)d_in[19];
  const float* b_prv  = (const float*)d_in[20];
  const float* w_po1  = (const float*)d_in[21];
  const float* b_po1  = (const float*)d_in[22];
  const float* w_po2  = (const float*)d_in[23];
  const float* b_po2  = (const float*)d_in[24];
  const float* w_pom  = (const float*)d_in[25];
  const float* b_pom  = (const float*)d_in[26];
  const float* w_pov  = (const float*)d_in[27];
  const float* b_pov  = (const float*)d_in[28];

  unsigned short* B1 = (unsigned short*)d_ws;                       // 65536x256 bf16
  unsigned short* WT = (unsigned short*)((char*)d_ws + B1_BYTES);   // shuffled tiles
  unsigned short* Hb  = WT + (size_t)TOT_TILES*512;                 // h_t (B*127 x 256)
  unsigned short* XS  = Hb + (size_t)BN*127*256;                    // s slices
  unsigned short* XG  = XS + 32*8*256;
  unsigned short* XH  = XG + 32*8*512;
  unsigned short* XM1 = XH + (size_t)2*32*8*512;
  unsigned short* XM2 = XM1 + 32*8*512;
  unsigned*       CNT = (unsigned*)(XM2 + 32*8*512);                // 4KB agent counters
  unsigned*       FCNT = (unsigned*)((char*)CNT + 4096);            // 8KB fast counters
  unsigned*       XCC  = (unsigned*)((char*)FCNT + 8192);           // 1KB xcc publish

  ShufArgs sa;
  const float* srcs[14] = {w_obs1, w_obs2, w_po1, w_po1, w_gin, w_ih, w_hh,
                           w_pr1, w_pr2, w_prm, w_prv, w_po2, w_pom, w_pov};
  const int strides[14] = {512,256,512,512,136,256,256,256,256,256,256,256,256,256};
  const int coloffs[14] = {0,0,256,0,0,0,0,0,0,0,0,0,0,0};
  const int ktl[14]     = {16,8,8,8,4,8,8,8,8,8,8,8,8,8};
  const int tbas[14]    = {OBS1_T,OBS2_T,PO1O_T,PO1H_T,GINS_T,IH_T,HH_T,
                           PR1_T,PR2_T,PRM_T,PRV_T,PO2_T,POM_T,POV_T};
  const int tcnt[14]    = {256,128,128,128,64,384,384,128,128,64,64,128,64,64};
  for (int i = 0; i < 14; i++){
    sa.src[i] = srcs[i]; sa.stride[i] = strides[i]; sa.coloff[i] = coloffs[i];
    sa.ktiles[i] = ktl[i]; sa.tbase[i] = tbas[i]; sa.tcnt[i] = tcnt[i];
  }
  shuffle_w<<<TOT_TILES, 64, 0, stream>>>(sa, WT);

  // obs MLP + po1_o, all in-place in B1 (rows are block-exclusive)
  big_gemm<<<1024, 256, 0, stream>>>(vis, 1, 512, WT, OBS1_T, b_obs1, 1, B1);
  big_gemm<<<1024, 256, 0, stream>>>(B1,  0, 256, WT, OBS2_T, b_obs2, 1, B1);
  big_gemm<<<1024, 256, 0, stream>>>(B1,  0, 256, WT, PO1O_T, b_po1,  0, B1);

  // zero H parity buffers + barrier counters (replayed each graph run;
  // inter-kernel L2 writeback/invalidate at dispatch boundaries makes the
  // SDMA memsets visible to both fast (L2) and slow (MALL) paths)
  hipMemsetAsync(XH, 0, (size_t)2*32*8*512*2, stream);
  hipMemsetAsync(CNT, 0, 4096, stream);
  hipMemsetAsync(FCNT, 0, 8192, stream);

  RnnArgs ra;
  ra.wt = WT; ra.Pbuf = B1;
  ra.actions = acts; ra.noise = noise; ra.w_gin = w_gin;
  ra.b_gin = b_gin; ra.b_ih = b_ih; ra.b_hh = b_hh;
  ra.b_po2 = b_po2; ra.b_pom = b_pom; ra.b_pov = b_pov;
  ra.Hb = Hb; ra.XS = XS; ra.XG = XG; ra.XH = XH; ra.XM1 = XM1; ra.XM2 = XM2;
  ra.cnt = CNT; ra.fcnt = FCNT; ra.xcc = XCC; ra.out = (float*)d_out;
  rssm_rnn<<<256, 128, 0, stream>>>(ra);

  post_pass<<<4064, 1024, 0, stream>>>(WT, B1, Hb, b_pr1, b_pr2, b_prm, b_prv,
                                       b_po2, b_pom, b_pov, (float*)d_out);
}